// Round 1
// baseline (938.109 us; speedup 1.0000x reference)
//
#include <hip/hip_runtime.h>

typedef unsigned short u16;
typedef unsigned int   u32;
typedef short v8s __attribute__((ext_vector_type(8)));
typedef float v4f __attribute__((ext_vector_type(4)));

#define DIMM 2048
#define NH   16
#define NKV  4
#define HD   128
#define BB   8
#define SS   1024
#define KVD  (NKV*HD)   // 512
#define SCALE 0.08838834764831845f

__device__ __forceinline__ u16 f2b(float f) {
  u32 u = __builtin_bit_cast(u32, f);
  u32 r = (u + 0x7FFFu + ((u >> 16) & 1u)) >> 16;
  return (u16)r;
}
__device__ __forceinline__ float b2f(u16 h) {
  return __builtin_bit_cast(float, (u32)h << 16);
}

typedef const u32 __attribute__((address_space(1)))* gp_t;
typedef u32 __attribute__((address_space(3)))* lp_t;
__device__ __forceinline__ void async16(const u16* g, u16* l) {
  __builtin_amdgcn_global_load_lds((gp_t)g, (lp_t)l, 16, 0, 0);
}

// ---------------- convert f32 -> bf16 (x, wq, wk, wv, wo) ----------------
// chunk = 8 elements. cum chunks: x 2097152 | wq 524288 | wk 131072 | wv 131072 | wo 524288
__global__ __launch_bounds__(256) void convert_all(
    const float* __restrict__ x, const float* __restrict__ wq,
    const float* __restrict__ wk, const float* __restrict__ wv,
    const float* __restrict__ wo,
    u16* __restrict__ xb, u16* __restrict__ wqb, u16* __restrict__ wkb,
    u16* __restrict__ wvb, u16* __restrict__ wob) {
  u32 t = blockIdx.x * 256u + threadIdx.x;
  const float* src; u16* dst; u32 lc;
  if      (t < 2097152u) { src = x;  dst = xb;  lc = t; }
  else if (t < 2621440u) { src = wq; dst = wqb; lc = t - 2097152u; }
  else if (t < 2752512u) { src = wk; dst = wkb; lc = t - 2621440u; }
  else if (t < 2883584u) { src = wv; dst = wvb; lc = t - 2752512u; }
  else                   { src = wo; dst = wob; lc = t - 2883584u; }
  size_t e = (size_t)lc * 8;
  float4 a = *(const float4*)(src + e);
  float4 b = *(const float4*)(src + e + 4);
  uint4 o;
  o.x = (u32)f2b(a.x) | ((u32)f2b(a.y) << 16);
  o.y = (u32)f2b(a.z) | ((u32)f2b(a.w) << 16);
  o.z = (u32)f2b(b.x) | ((u32)f2b(b.y) << 16);
  o.w = (u32)f2b(b.z) | ((u32)f2b(b.w) << 16);
  *(uint4*)(dst + e) = o;
}

// ---------------- GEMM: C(M,N) = A(M,K) @ B(N,K)^T, bf16 in, f32 acc ----------------
template<int OUTF>
__global__ __launch_bounds__(256) void gemm_bt(
    const u16* __restrict__ A, const u16* __restrict__ Bw,
    float* __restrict__ Cf, u16* __restrict__ Cb, int M, int N, int K) {
  __shared__ u16 As[4096];
  __shared__ u16 Bs[4096];
  int wave = threadIdx.x >> 6, lane = threadIdx.x & 63;
  int lo = lane & 15, hi = lane >> 4;
  int wm = wave >> 1, wn = wave & 1;
  int m0 = blockIdx.y * 128, n0 = blockIdx.x * 128;
  v4f acc[4][4] = {};
  for (int k0 = 0; k0 < K; k0 += 32) {
    __syncthreads();
#pragma unroll
    for (int j = 0; j < 2; ++j) {
      int base = (j * 4 + wave) * 512;
      int l = base + lane * 8;
      int row = l >> 5, col = l & 31;
      async16(A  + (size_t)(m0 + row) * K + k0 + col, &As[base]);
      async16(Bw + (size_t)(n0 + row) * K + k0 + col, &Bs[base]);
    }
    __syncthreads();
    v8s af[4], bf[4];
#pragma unroll
    for (int t = 0; t < 4; ++t) {
      af[t] = *(const v8s*)&As[(wm * 64 + t * 16 + lo) * 32 + hi * 8];
      bf[t] = *(const v8s*)&Bs[(wn * 64 + t * 16 + lo) * 32 + hi * 8];
    }
#pragma unroll
    for (int mt = 0; mt < 4; ++mt)
#pragma unroll
      for (int nt = 0; nt < 4; ++nt)
        acc[mt][nt] = __builtin_amdgcn_mfma_f32_16x16x32_bf16(af[mt], bf[nt], acc[mt][nt], 0, 0, 0);
  }
#pragma unroll
  for (int mt = 0; mt < 4; ++mt)
#pragma unroll
    for (int nt = 0; nt < 4; ++nt)
#pragma unroll
      for (int r = 0; r < 4; ++r) {
        int row = m0 + wm * 64 + mt * 16 + 4 * hi + r;
        int col = n0 + wn * 64 + nt * 16 + lo;
        if (OUTF) Cf[(size_t)row * N + col] = acc[mt][nt][r];
        else      Cb[(size_t)row * N + col] = f2b(acc[mt][nt][r]);
      }
}

// ---------------- RoPE on Q (2048 wide) and K (512 wide), bf16 in-place ----------------
// chunk = 4 pairs = 8 bf16. Q chunks: 2097152, K chunks: 524288.
__global__ __launch_bounds__(256) void rope_all(
    u16* __restrict__ Qb, u16* __restrict__ Kb,
    const float* __restrict__ fc, const float* __restrict__ fs) {
  u32 t = blockIdx.x * 256u + threadIdx.x;
  u16* buf; u32 row, c8, stride;
  if (t < 2097152u) { buf = Qb; row = t >> 8; c8 = (t & 255u) * 8u; stride = 2048u; }
  else { u32 lc = t - 2097152u; buf = Kb; row = lc >> 6; c8 = (lc & 63u) * 8u; stride = 512u; }
  u32 sp = row & 1023u;
  u32 j0 = (c8 & 127u) >> 1;
  float4 c = *(const float4*)(fc + (size_t)sp * 64 + j0);
  float4 s = *(const float4*)(fs + (size_t)sp * 64 + j0);
  u16* p = buf + (size_t)row * stride + c8;
  uint4 w = *(const uint4*)p;
  u32 wv_[4] = {w.x, w.y, w.z, w.w};
  float cc[4] = {c.x, c.y, c.z, c.w};
  float ss2[4] = {s.x, s.y, s.z, s.w};
#pragma unroll
  for (int i = 0; i < 4; ++i) {
    float tr = b2f((u16)(wv_[i] & 0xFFFFu));
    float ti = b2f((u16)(wv_[i] >> 16));
    float orr = tr * cc[i] - ti * ss2[i];
    float oi  = tr * ss2[i] + ti * cc[i];
    wv_[i] = (u32)f2b(orr) | ((u32)f2b(oi) << 16);
  }
  uint4 o; o.x = wv_[0]; o.y = wv_[1]; o.z = wv_[2]; o.w = wv_[3];
  *(uint4*)p = o;
}

// ---------------- Flash attention, causal, GQA ----------------
// grid: B*NH*(S/64) = 2048 blocks; 4 waves/block, wave handles 16 q-rows.
__global__ __launch_bounds__(256) void attn(
    const u16* __restrict__ Q, const u16* __restrict__ Kb,
    const u16* __restrict__ Vb, u16* __restrict__ AO) {
  __shared__ u16 plds[4][16 * 32];
  int blk = blockIdx.x;
  int qc = blk & 15;
  int h  = (blk >> 4) & 15;
  int b  = blk >> 8;
  int wave = threadIdx.x >> 6;
  int lane = threadIdx.x & 63;
  int lo = lane & 15, hi = lane >> 4;
  int q0 = qc * 64 + wave * 16;
  int kvh = h >> 2;
  const u16* Qp = Q  + (size_t)b * SS * DIMM + (size_t)h * HD;
  const u16* Kp = Kb + (size_t)b * SS * KVD + (size_t)kvh * HD;
  const u16* Vp = Vb + (size_t)b * SS * KVD + (size_t)kvh * HD;

  v8s qf[4];
#pragma unroll
  for (int ks = 0; ks < 4; ++ks)
    qf[ks] = *(const v8s*)(Qp + (size_t)(q0 + lo) * DIMM + ks * 32 + hi * 8);

  float M[4], L[4];
  v4f oacc[8];
#pragma unroll
  for (int r = 0; r < 4; ++r) { M[r] = -1e30f; L[r] = 0.f; }
#pragma unroll
  for (int nt = 0; nt < 8; ++nt) oacc[nt] = (v4f){0.f, 0.f, 0.f, 0.f};

  int kv_end = q0 + 16;
  for (int kv0 = 0; kv0 < kv_end; kv0 += 32) {
    v4f sacc0 = (v4f){0.f, 0.f, 0.f, 0.f};
    v4f sacc1 = (v4f){0.f, 0.f, 0.f, 0.f};
#pragma unroll
    for (int ks = 0; ks < 4; ++ks) {
      v8s kf0 = *(const v8s*)(Kp + (size_t)(kv0 + lo) * KVD + ks * 32 + hi * 8);
      sacc0 = __builtin_amdgcn_mfma_f32_16x16x32_bf16(qf[ks], kf0, sacc0, 0, 0, 0);
      v8s kf1 = *(const v8s*)(Kp + (size_t)(kv0 + 16 + lo) * KVD + ks * 32 + hi * 8);
      sacc1 = __builtin_amdgcn_mfma_f32_16x16x32_bf16(qf[ks], kf1, sacc1, 0, 0, 0);
    }
    float p0[4], p1[4], al[4];
#pragma unroll
    for (int r = 0; r < 4; ++r) {
      int qg = q0 + 4 * hi + r;
      float s0 = sacc0[r] * SCALE, s1 = sacc1[r] * SCALE;
      if (kv0 + lo > qg)      s0 = -1e30f;
      if (kv0 + 16 + lo > qg) s1 = -1e30f;
      float mx = fmaxf(s0, s1);
      mx = fmaxf(mx, __shfl_xor(mx, 1));
      mx = fmaxf(mx, __shfl_xor(mx, 2));
      mx = fmaxf(mx, __shfl_xor(mx, 4));
      mx = fmaxf(mx, __shfl_xor(mx, 8));
      float mnew = fmaxf(M[r], mx);
      float a = __expf(M[r] - mnew);
      M[r] = mnew; al[r] = a;
      float e0 = __expf(s0 - mnew), e1 = __expf(s1 - mnew);
      p0[r] = e0; p1[r] = e1;
      float ps = e0 + e1;
      ps += __shfl_xor(ps, 1);
      ps += __shfl_xor(ps, 2);
      ps += __shfl_xor(ps, 4);
      ps += __shfl_xor(ps, 8);
      L[r] = L[r] * a + ps;
    }
#pragma unroll
    for (int nt = 0; nt < 8; ++nt)
#pragma unroll
      for (int r = 0; r < 4; ++r)
        oacc[nt][r] *= al[r];
    // P (D-layout) -> LDS -> A-layout fragment
#pragma unroll
    for (int r = 0; r < 4; ++r) {
      plds[wave][(4 * hi + r) * 32 + lo]      = f2b(p0[r]);
      plds[wave][(4 * hi + r) * 32 + 16 + lo] = f2b(p1[r]);
    }
    v8s pf = *(const v8s*)&plds[wave][lo * 32 + hi * 8];
#pragma unroll
    for (int nt = 0; nt < 8; ++nt) {
      v8s vf;
#pragma unroll
      for (int j = 0; j < 8; ++j)
        vf[j] = (short)Vp[(size_t)(kv0 + 8 * hi + j) * KVD + nt * 16 + lo];
      oacc[nt] = __builtin_amdgcn_mfma_f32_16x16x32_bf16(pf, vf, oacc[nt], 0, 0, 0);
    }
  }
  u16* Op = AO + (size_t)b * SS * DIMM + (size_t)h * HD;
#pragma unroll
  for (int nt = 0; nt < 8; ++nt)
#pragma unroll
    for (int r = 0; r < 4; ++r)
      Op[(size_t)(q0 + 4 * hi + r) * DIMM + nt * 16 + lo] = f2b(oacc[nt][r] / L[r]);
}

extern "C" void kernel_launch(void* const* d_in, const int* in_sizes, int n_in,
                              void* d_out, int out_size, void* d_ws, size_t ws_size,
                              hipStream_t stream) {
  const float* x  = (const float*)d_in[0];
  const float* fc = (const float*)d_in[1];
  const float* fs = (const float*)d_in[2];
  const float* wq = (const float*)d_in[3];
  const float* wk = (const float*)d_in[4];
  const float* wv = (const float*)d_in[5];
  const float* wo = (const float*)d_in[6];
  float* out = (float*)d_out;

  u16* ws  = (u16*)d_ws;
  u16* xb  = ws;               // 16777216
  u16* wqb = xb  + 16777216;   // 4194304
  u16* wkb = wqb + 4194304;    // 1048576
  u16* wvb = wkb + 1048576;    // 1048576
  u16* wob = wvb + 1048576;    // 4194304
  u16* qb  = wob + 4194304;    // 16777216
  u16* kb  = qb  + 16777216;   // 4194304
  u16* vb  = kb  + 4194304;    // 4194304
  u16* ao  = vb  + 4194304;    // 16777216

  convert_all<<<13312, 256, 0, stream>>>(x, wq, wk, wv, wo, xb, wqb, wkb, wvb, wob);
  gemm_bt<0><<<dim3(16, 64), 256, 0, stream>>>(xb, wqb, nullptr, qb, 8192, 2048, 2048);
  gemm_bt<0><<<dim3(4, 64),  256, 0, stream>>>(xb, wkb, nullptr, kb, 8192, 512, 2048);
  gemm_bt<0><<<dim3(4, 64),  256, 0, stream>>>(xb, wvb, nullptr, vb, 8192, 512, 2048);
  rope_all<<<10240, 256, 0, stream>>>(qb, kb, fc, fs);
  attn<<<2048, 256, 0, stream>>>(qb, kb, vb, ao);
  gemm_bt<1><<<dim3(16, 64), 256, 0, stream>>>(ao, wob, out, nullptr, 8192, 2048, 2048);
}

// Round 4
// 910.706 us; speedup vs baseline: 1.0301x; 1.0301x over previous
//
#include <hip/hip_runtime.h>

typedef unsigned short u16;
typedef unsigned int   u32;
typedef short v8s __attribute__((ext_vector_type(8)));
typedef float v4f __attribute__((ext_vector_type(4)));

#define DIMM 2048
#define NH   16
#define NKV  4
#define HD   128
#define BB   8
#define SS   1024
#define KVD  (NKV*HD)   // 512
#define SCALE 0.08838834764831845f
#define PST  72         // plds row stride (u16), padded vs 64 to avoid bank conflicts

__device__ __forceinline__ u16 f2b(float f) {
  u32 u = __builtin_bit_cast(u32, f);
  u32 r = (u + 0x7FFFu + ((u >> 16) & 1u)) >> 16;
  return (u16)r;
}
__device__ __forceinline__ float b2f(u16 h) {
  return __builtin_bit_cast(float, (u32)h << 16);
}

typedef const u32 __attribute__((address_space(1)))* gp_t;
typedef u32 __attribute__((address_space(3)))* lp_t;
__device__ __forceinline__ void async16(const u16* g, u16* l) {
  __builtin_amdgcn_global_load_lds((gp_t)g, (lp_t)l, 16, 0, 0);
}

// ---------------- convert f32 -> bf16 (x, wq, wk, wv, wo) ----------------
__global__ __launch_bounds__(256) void convert_all(
    const float* __restrict__ x, const float* __restrict__ wq,
    const float* __restrict__ wk, const float* __restrict__ wv,
    const float* __restrict__ wo,
    u16* __restrict__ xb, u16* __restrict__ wqb, u16* __restrict__ wkb,
    u16* __restrict__ wvb, u16* __restrict__ wob) {
  u32 t = blockIdx.x * 256u + threadIdx.x;
  const float* src; u16* dst; u32 lc;
  if      (t < 2097152u) { src = x;  dst = xb;  lc = t; }
  else if (t < 2621440u) { src = wq; dst = wqb; lc = t - 2097152u; }
  else if (t < 2752512u) { src = wk; dst = wkb; lc = t - 2621440u; }
  else if (t < 2883584u) { src = wv; dst = wvb; lc = t - 2752512u; }
  else                   { src = wo; dst = wob; lc = t - 2883584u; }
  size_t e = (size_t)lc * 8;
  float4 a = *(const float4*)(src + e);
  float4 b = *(const float4*)(src + e + 4);
  uint4 o;
  o.x = (u32)f2b(a.x) | ((u32)f2b(a.y) << 16);
  o.y = (u32)f2b(a.z) | ((u32)f2b(a.w) << 16);
  o.z = (u32)f2b(b.x) | ((u32)f2b(b.y) << 16);
  o.w = (u32)f2b(b.z) | ((u32)f2b(b.w) << 16);
  *(uint4*)(dst + e) = o;
}

// ---------------- GEMM: C(M,N) = A(M,K) @ B(N,K)^T, bf16 in, f32 acc ----------------
template<int OUTF>
__global__ __launch_bounds__(256) void gemm_bt(
    const u16* __restrict__ A, const u16* __restrict__ Bw,
    float* __restrict__ Cf, u16* __restrict__ Cb, int M, int N, int K) {
  __shared__ u16 As[4096];
  __shared__ u16 Bs[4096];
  int wave = threadIdx.x >> 6, lane = threadIdx.x & 63;
  int lo = lane & 15, hi = lane >> 4;
  int wm = wave >> 1, wn = wave & 1;
  int m0 = blockIdx.y * 128, n0 = blockIdx.x * 128;
  v4f acc[4][4] = {};
  for (int k0 = 0; k0 < K; k0 += 32) {
    __syncthreads();
#pragma unroll
    for (int j = 0; j < 2; ++j) {
      int base = (j * 4 + wave) * 512;
      int l = base + lane * 8;
      int row = l >> 5, col = l & 31;
      async16(A  + (size_t)(m0 + row) * K + k0 + col, &As[base]);
      async16(Bw + (size_t)(n0 + row) * K + k0 + col, &Bs[base]);
    }
    __syncthreads();
    v8s af[4], bf[4];
#pragma unroll
    for (int t = 0; t < 4; ++t) {
      af[t] = *(const v8s*)&As[(wm * 64 + t * 16 + lo) * 32 + hi * 8];
      bf[t] = *(const v8s*)&Bs[(wn * 64 + t * 16 + lo) * 32 + hi * 8];
    }
#pragma unroll
    for (int mt = 0; mt < 4; ++mt)
#pragma unroll
      for (int nt = 0; nt < 4; ++nt)
        acc[mt][nt] = __builtin_amdgcn_mfma_f32_16x16x32_bf16(af[mt], bf[nt], acc[mt][nt], 0, 0, 0);
  }
#pragma unroll
  for (int mt = 0; mt < 4; ++mt)
#pragma unroll
    for (int nt = 0; nt < 4; ++nt)
#pragma unroll
      for (int r = 0; r < 4; ++r) {
        int row = m0 + wm * 64 + mt * 16 + 4 * hi + r;
        int col = n0 + wn * 64 + nt * 16 + lo;
        if (OUTF) Cf[(size_t)row * N + col] = acc[mt][nt][r];
        else      Cb[(size_t)row * N + col] = f2b(acc[mt][nt][r]);
      }
}

// ---------------- RoPE on Q (2048 wide) and K (512 wide), bf16 in-place ----------------
__global__ __launch_bounds__(256) void rope_all(
    u16* __restrict__ Qb, u16* __restrict__ Kb,
    const float* __restrict__ fc, const float* __restrict__ fs) {
  u32 t = blockIdx.x * 256u + threadIdx.x;
  u16* buf; u32 row, c8, stride;
  if (t < 2097152u) { buf = Qb; row = t >> 8; c8 = (t & 255u) * 8u; stride = 2048u; }
  else { u32 lc = t - 2097152u; buf = Kb; row = lc >> 6; c8 = (lc & 63u) * 8u; stride = 512u; }
  u32 sp = row & 1023u;
  u32 j0 = (c8 & 127u) >> 1;
  float4 c = *(const float4*)(fc + (size_t)sp * 64 + j0);
  float4 s = *(const float4*)(fs + (size_t)sp * 64 + j0);
  u16* p = buf + (size_t)row * stride + c8;
  uint4 w = *(const uint4*)p;
  u32 wv_[4] = {w.x, w.y, w.z, w.w};
  float cc[4] = {c.x, c.y, c.z, c.w};
  float ss2[4] = {s.x, s.y, s.z, s.w};
#pragma unroll
  for (int i = 0; i < 4; ++i) {
    float tr = b2f((u16)(wv_[i] & 0xFFFFu));
    float ti = b2f((u16)(wv_[i] >> 16));
    float orr = tr * cc[i] - ti * ss2[i];
    float oi  = tr * ss2[i] + ti * cc[i];
    wv_[i] = (u32)f2b(orr) | ((u32)f2b(oi) << 16);
  }
  uint4 o; o.x = wv_[0]; o.y = wv_[1]; o.z = wv_[2]; o.w = wv_[3];
  *(uint4*)p = o;
}

// ---------------- V transpose: vb[b][s][kvh*128+d] -> vt[b][kvh][d][s] ----------------
// 64x64 tiles through LDS; row stride 66 u16 (33 u32) to spread banks.
__global__ __launch_bounds__(256) void transpose_v(
    const u16* __restrict__ vb, u16* __restrict__ vt) {
  __shared__ u32 t32[64][33];
  int blk = blockIdx.x;
  int dt = blk & 1, st = (blk >> 1) & 15, kvh = (blk >> 5) & 3, b = blk >> 7;
  int s0 = st * 64, d0 = dt * 64;
  int tid = threadIdx.x;
  int r = tid >> 3, q = tid & 7;
  const u16* src = vb + (size_t)b * SS * KVD + (size_t)kvh * HD + d0;
#pragma unroll
  for (int p = 0; p < 2; ++p) {
    int row = p * 32 + r;
    uint4 v = *(const uint4*)(src + (size_t)(s0 + row) * KVD + q * 8);
    t32[row][q * 4 + 0] = v.x; t32[row][q * 4 + 1] = v.y;
    t32[row][q * 4 + 2] = v.z; t32[row][q * 4 + 3] = v.w;
  }
  __syncthreads();
  const u16* t16 = (const u16*)t32;
  u16* dst = vt + ((size_t)(b * NKV + kvh) * HD + d0) * SS + s0;
#pragma unroll
  for (int p = 0; p < 2; ++p) {
    int dd = p * 32 + r;
    u16 tmp[8];
#pragma unroll
    for (int j = 0; j < 8; ++j) tmp[j] = t16[(size_t)(q * 8 + j) * 66 + dd];
    *(uint4*)(dst + (size_t)dd * SS + q * 8) = *(uint4*)tmp;
  }
}

// ---------------- Flash attention, causal, GQA ----------------
// grid: B*NH*(S/64) = 2048 blocks; 4 waves/block, wave handles 16 q-rows, KV tile 64.
__global__ __launch_bounds__(256) void attn(
    const u16* __restrict__ Q, const u16* __restrict__ Kb,
    const u16* __restrict__ Vt, u16* __restrict__ AO) {
  __shared__ u16 plds[4][16 * PST];
  int blk = blockIdx.x;
  int qc = blk & 15;
  int h  = (blk >> 4) & 15;
  int b  = blk >> 8;
  int wave = threadIdx.x >> 6;
  int lane = threadIdx.x & 63;
  int lo = lane & 15, hi = lane >> 4;
  int q0 = qc * 64 + wave * 16;
  int kvh = h >> 2;
  const u16* Qp = Q  + (size_t)b * SS * DIMM + (size_t)h * HD;
  const u16* Kp = Kb + (size_t)b * SS * KVD + (size_t)kvh * HD;
  const u16* Vp = Vt + (size_t)(b * NKV + kvh) * HD * SS;   // [d][s]

  v8s qf[4];
#pragma unroll
  for (int ks = 0; ks < 4; ++ks)
    qf[ks] = *(const v8s*)(Qp + (size_t)(q0 + lo) * DIMM + ks * 32 + hi * 8);

  float M[4], L[4];
  v4f oacc[8];
#pragma unroll
  for (int r = 0; r < 4; ++r) { M[r] = -1e30f; L[r] = 0.f; }
#pragma unroll
  for (int nt = 0; nt < 8; ++nt) oacc[nt] = (v4f){0.f, 0.f, 0.f, 0.f};

  for (int kv0 = 0; kv0 < q0 + 16; kv0 += 64) {
    v4f sacc[4] = {(v4f){0,0,0,0},(v4f){0,0,0,0},(v4f){0,0,0,0},(v4f){0,0,0,0}};
#pragma unroll
    for (int ks = 0; ks < 4; ++ks)
#pragma unroll
      for (int t = 0; t < 4; ++t) {
        v8s kf = *(const v8s*)(Kp + (size_t)(kv0 + t * 16 + lo) * KVD + ks * 32 + hi * 8);
        sacc[t] = __builtin_amdgcn_mfma_f32_16x16x32_bf16(qf[ks], kf, sacc[t], 0, 0, 0);
      }
    bool masked = (kv0 + 64 > q0);
    float al[4], p[4][4];
#pragma unroll
    for (int r = 0; r < 4; ++r) {
      int qg = q0 + 4 * hi + r;
      float s_[4];
#pragma unroll
      for (int t = 0; t < 4; ++t) {
        s_[t] = sacc[t][r] * SCALE;
        if (masked && (kv0 + t * 16 + lo > qg)) s_[t] = -1e30f;
      }
      float mx = fmaxf(fmaxf(s_[0], s_[1]), fmaxf(s_[2], s_[3]));
      mx = fmaxf(mx, __shfl_xor(mx, 1));
      mx = fmaxf(mx, __shfl_xor(mx, 2));
      mx = fmaxf(mx, __shfl_xor(mx, 4));
      mx = fmaxf(mx, __shfl_xor(mx, 8));
      float mnew = fmaxf(M[r], mx);
      float a = __expf(M[r] - mnew);
      float ps = 0.f;
#pragma unroll
      for (int t = 0; t < 4; ++t) { p[r][t] = __expf(s_[t] - mnew); ps += p[r][t]; }
      ps += __shfl_xor(ps, 1);
      ps += __shfl_xor(ps, 2);
      ps += __shfl_xor(ps, 4);
      ps += __shfl_xor(ps, 8);
      M[r] = mnew; al[r] = a;
      L[r] = L[r] * a + ps;
    }
#pragma unroll
    for (int nt = 0; nt < 8; ++nt)
#pragma unroll
      for (int r = 0; r < 4; ++r) oacc[nt][r] *= al[r];
#pragma unroll
    for (int r = 0; r < 4; ++r)
#pragma unroll
      for (int t = 0; t < 4; ++t)
        plds[wave][(4 * hi + r) * PST + t * 16 + lo] = f2b(p[r][t]);
    v8s pf0 = *(const v8s*)&plds[wave][lo * PST + hi * 8];
    v8s pf1 = *(const v8s*)&plds[wave][lo * PST + 32 + hi * 8];
#pragma unroll
    for (int nt = 0; nt < 8; ++nt) {
      v8s vf0 = *(const v8s*)(Vp + (size_t)(nt * 16 + lo) * SS + kv0 + hi * 8);
      oacc[nt] = __builtin_amdgcn_mfma_f32_16x16x32_bf16(pf0, vf0, oacc[nt], 0, 0, 0);
      v8s vf1 = *(const v8s*)(Vp + (size_t)(nt * 16 + lo) * SS + kv0 + 32 + hi * 8);
      oacc[nt] = __builtin_amdgcn_mfma_f32_16x16x32_bf16(pf1, vf1, oacc[nt], 0, 0, 0);
    }
  }
  u16* Op = AO + (size_t)b * SS * DIMM + (size_t)h * HD;
#pragma unroll
  for (int nt = 0; nt < 8; ++nt)
#pragma unroll
    for (int r = 0; r < 4; ++r)
      Op[(size_t)(q0 + 4 * hi + r) * DIMM + nt * 16 + lo] = f2b(oacc[nt][r] / L[r]);
}

extern "C" void kernel_launch(void* const* d_in, const int* in_sizes, int n_in,
                              void* d_out, int out_size, void* d_ws, size_t ws_size,
                              hipStream_t stream) {
  const float* x  = (const float*)d_in[0];
  const float* fc = (const float*)d_in[1];
  const float* fs = (const float*)d_in[2];
  const float* wq = (const float*)d_in[3];
  const float* wk = (const float*)d_in[4];
  const float* wv = (const float*)d_in[5];
  const float* wo = (const float*)d_in[6];
  float* out = (float*)d_out;

  u16* ws  = (u16*)d_ws;
  u16* xb  = ws;               // 16777216
  u16* wqb = xb  + 16777216;   // 4194304
  u16* wkb = wqb + 4194304;    // 1048576
  u16* wvb = wkb + 1048576;    // 1048576
  u16* wob = wvb + 1048576;    // 4194304
  u16* qb  = wob + 4194304;    // 16777216
  u16* kb  = qb  + 16777216;   // 4194304
  u16* vb  = kb  + 4194304;    // 4194304
  u16* ao  = vb  + 4194304;    // 16777216
  u16* vtb = wqb;              // alias: wqb dead after Q GEMM; 4194304 u16 needed

  convert_all<<<13312, 256, 0, stream>>>(x, wq, wk, wv, wo, xb, wqb, wkb, wvb, wob);
  gemm_bt<0><<<dim3(16, 64), 256, 0, stream>>>(xb, wqb, nullptr, qb, 8192, 2048, 2048);
  gemm_bt<0><<<dim3(4, 64),  256, 0, stream>>>(xb, wkb, nullptr, kb, 8192, 512, 2048);
  gemm_bt<0><<<dim3(4, 64),  256, 0, stream>>>(xb, wvb, nullptr, vb, 8192, 512, 2048);
  rope_all<<<10240, 256, 0, stream>>>(qb, kb, fc, fs);
  transpose_v<<<1024, 256, 0, stream>>>(vb, vtb);
  attn<<<2048, 256, 0, stream>>>(qb, kb, vtb, ao);
  gemm_bt<1><<<dim3(16, 64), 256, 0, stream>>>(ao, wob, out, nullptr, 8192, 2048, 2048);
}

// Round 5
// 639.366 us; speedup vs baseline: 1.4672x; 1.4244x over previous
//
#include <hip/hip_runtime.h>

typedef unsigned short u16;
typedef unsigned int   u32;
typedef short v8s __attribute__((ext_vector_type(8)));
typedef float v4f __attribute__((ext_vector_type(4)));

#define DIMM 2048
#define NH   16
#define NKV  4
#define HD   128
#define BB   8
#define SS   1024
#define KVD  (NKV*HD)   // 512
#define SCALE 0.08838834764831845f
#define PST  72         // plds row stride (u16), padded vs 64 to avoid bank conflicts

__device__ __forceinline__ u16 f2b(float f) {
  u32 u = __builtin_bit_cast(u32, f);
  u32 r = (u + 0x7FFFu + ((u >> 16) & 1u)) >> 16;
  return (u16)r;
}
__device__ __forceinline__ float b2f(u16 h) {
  return __builtin_bit_cast(float, (u32)h << 16);
}

typedef const u32 __attribute__((address_space(1)))* gp_t;
typedef u32 __attribute__((address_space(3)))* lp_t;
__device__ __forceinline__ void async16(const u16* g, u16* l) {
  __builtin_amdgcn_global_load_lds((gp_t)g, (lp_t)l, 16, 0, 0);
}

// ---------------- convert f32 -> bf16 (x, wq, wk, wv, wo) ----------------
__global__ __launch_bounds__(256) void convert_all(
    const float* __restrict__ x, const float* __restrict__ wq,
    const float* __restrict__ wk, const float* __restrict__ wv,
    const float* __restrict__ wo,
    u16* __restrict__ xb, u16* __restrict__ wqb, u16* __restrict__ wkb,
    u16* __restrict__ wvb, u16* __restrict__ wob) {
  u32 t = blockIdx.x * 256u + threadIdx.x;
  const float* src; u16* dst; u32 lc;
  if      (t < 2097152u) { src = x;  dst = xb;  lc = t; }
  else if (t < 2621440u) { src = wq; dst = wqb; lc = t - 2097152u; }
  else if (t < 2752512u) { src = wk; dst = wkb; lc = t - 2621440u; }
  else if (t < 2883584u) { src = wv; dst = wvb; lc = t - 2752512u; }
  else                   { src = wo; dst = wob; lc = t - 2883584u; }
  size_t e = (size_t)lc * 8;
  float4 a = *(const float4*)(src + e);
  float4 b = *(const float4*)(src + e + 4);
  uint4 o;
  o.x = (u32)f2b(a.x) | ((u32)f2b(a.y) << 16);
  o.y = (u32)f2b(a.z) | ((u32)f2b(a.w) << 16);
  o.z = (u32)f2b(b.x) | ((u32)f2b(b.y) << 16);
  o.w = (u32)f2b(b.z) | ((u32)f2b(b.w) << 16);
  *(uint4*)(dst + e) = o;
}

// ---------------- GEMM: C(M,N) = A(M,K) @ B(N,K)^T, bf16 in, f32 acc ----------------
template<int OUTF>
__global__ __launch_bounds__(256) void gemm_bt(
    const u16* __restrict__ A, const u16* __restrict__ Bw,
    float* __restrict__ Cf, u16* __restrict__ Cb, int M, int N, int K) {
  __shared__ u16 As[4096];
  __shared__ u16 Bs[4096];
  int wave = threadIdx.x >> 6, lane = threadIdx.x & 63;
  int lo = lane & 15, hi = lane >> 4;
  int wm = wave >> 1, wn = wave & 1;
  int m0 = blockIdx.y * 128, n0 = blockIdx.x * 128;
  v4f acc[4][4] = {};
  for (int k0 = 0; k0 < K; k0 += 32) {
    __syncthreads();
#pragma unroll
    for (int j = 0; j < 2; ++j) {
      int base = (j * 4 + wave) * 512;
      int l = base + lane * 8;
      int row = l >> 5, col = l & 31;
      async16(A  + (size_t)(m0 + row) * K + k0 + col, &As[base]);
      async16(Bw + (size_t)(n0 + row) * K + k0 + col, &Bs[base]);
    }
    __syncthreads();
    v8s af[4], bf[4];
#pragma unroll
    for (int t = 0; t < 4; ++t) {
      af[t] = *(const v8s*)&As[(wm * 64 + t * 16 + lo) * 32 + hi * 8];
      bf[t] = *(const v8s*)&Bs[(wn * 64 + t * 16 + lo) * 32 + hi * 8];
    }
#pragma unroll
    for (int mt = 0; mt < 4; ++mt)
#pragma unroll
      for (int nt = 0; nt < 4; ++nt)
        acc[mt][nt] = __builtin_amdgcn_mfma_f32_16x16x32_bf16(af[mt], bf[nt], acc[mt][nt], 0, 0, 0);
  }
#pragma unroll
  for (int mt = 0; mt < 4; ++mt)
#pragma unroll
    for (int nt = 0; nt < 4; ++nt)
#pragma unroll
      for (int r = 0; r < 4; ++r) {
        int row = m0 + wm * 64 + mt * 16 + 4 * hi + r;
        int col = n0 + wn * 64 + nt * 16 + lo;
        if (OUTF) Cf[(size_t)row * N + col] = acc[mt][nt][r];
        else      Cb[(size_t)row * N + col] = f2b(acc[mt][nt][r]);
      }
}

// ---------------- RoPE on Q (2048 wide) and K (512 wide), bf16 in-place ----------------
__global__ __launch_bounds__(256) void rope_all(
    u16* __restrict__ Qb, u16* __restrict__ Kb,
    const float* __restrict__ fc, const float* __restrict__ fs) {
  u32 t = blockIdx.x * 256u + threadIdx.x;
  u16* buf; u32 row, c8, stride;
  if (t < 2097152u) { buf = Qb; row = t >> 8; c8 = (t & 255u) * 8u; stride = 2048u; }
  else { u32 lc = t - 2097152u; buf = Kb; row = lc >> 6; c8 = (lc & 63u) * 8u; stride = 512u; }
  u32 sp = row & 1023u;
  u32 j0 = (c8 & 127u) >> 1;
  float4 c = *(const float4*)(fc + (size_t)sp * 64 + j0);
  float4 s = *(const float4*)(fs + (size_t)sp * 64 + j0);
  u16* p = buf + (size_t)row * stride + c8;
  uint4 w = *(const uint4*)p;
  u32 wv_[4] = {w.x, w.y, w.z, w.w};
  float cc[4] = {c.x, c.y, c.z, c.w};
  float ss2[4] = {s.x, s.y, s.z, s.w};
#pragma unroll
  for (int i = 0; i < 4; ++i) {
    float tr = b2f((u16)(wv_[i] & 0xFFFFu));
    float ti = b2f((u16)(wv_[i] >> 16));
    float orr = tr * cc[i] - ti * ss2[i];
    float oi  = tr * ss2[i] + ti * cc[i];
    wv_[i] = (u32)f2b(orr) | ((u32)f2b(oi) << 16);
  }
  uint4 o; o.x = wv_[0]; o.y = wv_[1]; o.z = wv_[2]; o.w = wv_[3];
  *(uint4*)p = o;
}

// ---------------- V transpose: vb[b][s][kvh*128+d] -> vt[b][kvh][d][s] ----------------
__global__ __launch_bounds__(256) void transpose_v(
    const u16* __restrict__ vb, u16* __restrict__ vt) {
  __shared__ u32 t32[64][33];
  int blk = blockIdx.x;
  int dt = blk & 1, st = (blk >> 1) & 15, kvh = (blk >> 5) & 3, b = blk >> 7;
  int s0 = st * 64, d0 = dt * 64;
  int tid = threadIdx.x;
  int r = tid >> 3, q = tid & 7;
  const u16* src = vb + (size_t)b * SS * KVD + (size_t)kvh * HD + d0;
#pragma unroll
  for (int p = 0; p < 2; ++p) {
    int row = p * 32 + r;
    uint4 v = *(const uint4*)(src + (size_t)(s0 + row) * KVD + q * 8);
    t32[row][q * 4 + 0] = v.x; t32[row][q * 4 + 1] = v.y;
    t32[row][q * 4 + 2] = v.z; t32[row][q * 4 + 3] = v.w;
  }
  __syncthreads();
  const u16* t16 = (const u16*)t32;
  u16* dst = vt + ((size_t)(b * NKV + kvh) * HD + d0) * SS + s0;
#pragma unroll
  for (int p = 0; p < 2; ++p) {
    int dd = p * 32 + r;
    u16 tmp[8];
#pragma unroll
    for (int j = 0; j < 8; ++j) tmp[j] = t16[(size_t)(q * 8 + j) * 66 + dd];
    *(uint4*)(dst + (size_t)dd * SS + q * 8) = *(uint4*)tmp;
  }
}

// ---------------- Flash attention, causal, GQA ----------------
// grid: B*NH*(S/64) = 2048 blocks; 4 waves/block, wave owns 16 q-rows.
// K/V^T tiles staged in LDS per-block (shared by 4 waves), double-buffered,
// XOR-swizzled via pre-swizzled global source (rule #21). One vmcnt(0)+raw
// s_barrier per tile (T3-minimum) so stage(t+1) flies under compute(t).
__global__ __launch_bounds__(256) void attn(
    const u16* __restrict__ Q, const u16* __restrict__ Kb,
    const u16* __restrict__ Vt, u16* __restrict__ AO) {
  __shared__ u16 Ksh[2][64 * 128];   // [kv][d], row = 16 slots of 16B
  __shared__ u16 Vsh[2][128 * 64];   // [d][kv], row = 8 slots of 16B
  __shared__ u16 plds[4][16 * PST];
  int blk = blockIdx.x;
  int qc = blk & 15;
  int h  = (blk >> 4) & 15;
  int b  = blk >> 8;
  int wave = threadIdx.x >> 6;
  int lane = threadIdx.x & 63;
  int lo = lane & 15, hi = lane >> 4;
  int q0 = qc * 64 + wave * 16;
  int kvh = h >> 2;
  const u16* Qp = Q  + (size_t)b * SS * DIMM + (size_t)h * HD;
  const u16* Kp = Kb + (size_t)b * SS * KVD + (size_t)kvh * HD;
  const u16* Vp = Vt + (size_t)(b * NKV + kvh) * HD * SS;   // [d][s]

  // staging constants: wave stages K instrs [wave*4, wave*4+4) and same for V
  int l4 = lane >> 4, l4s = lane & 15;   // K: 4 rows/instr, 16 slots/row
  int l8 = lane >> 3, l8s = lane & 7;    // V: 8 rows/instr, 8 slots/row

  v8s qf[4];
#pragma unroll
  for (int ks = 0; ks < 4; ++ks)
    qf[ks] = *(const v8s*)(Qp + (size_t)(q0 + lo) * DIMM + ks * 32 + hi * 8);

  float M[4], L[4];
  v4f oacc[8];
#pragma unroll
  for (int r = 0; r < 4; ++r) { M[r] = -1e30f; L[r] = 0.f; }
#pragma unroll
  for (int nt = 0; nt < 8; ++nt) oacc[nt] = (v4f){0.f, 0.f, 0.f, 0.f};

  int NT = qc + 1;   // same tile count for all 4 waves

  // prologue: stage tile 0 into buf 0
#pragma unroll
  for (int i = 0; i < 4; ++i) {
    int instr = wave * 4 + i;
    int row = instr * 4 + l4;
    async16(Kp + (size_t)row * KVD + ((l4s ^ (row & 7)) * 8), &Ksh[0][instr * 512]);
    int d = instr * 8 + l8;
    async16(Vp + (size_t)d * SS + ((l8s ^ (d & 7)) * 8), &Vsh[0][instr * 512]);
  }
  asm volatile("s_waitcnt vmcnt(0)" ::: "memory");
  __builtin_amdgcn_s_barrier();
  __builtin_amdgcn_sched_barrier(0);

  int cur = 0;
  for (int t = 0; t < NT; ++t) {
    int kv0 = t * 64;
    if (t + 1 < NT) {
      int kv1 = kv0 + 64;
#pragma unroll
      for (int i = 0; i < 4; ++i) {
        int instr = wave * 4 + i;
        int row = instr * 4 + l4;
        async16(Kp + (size_t)(kv1 + row) * KVD + ((l4s ^ (row & 7)) * 8),
                &Ksh[cur ^ 1][instr * 512]);
        int d = instr * 8 + l8;
        async16(Vp + (size_t)d * SS + kv1 + ((l8s ^ (d & 7)) * 8),
                &Vsh[cur ^ 1][instr * 512]);
      }
    }
    const u16* Kbuf = Ksh[cur];
    const u16* Vbuf = Vsh[cur];
    // ---- QK^T from LDS (swizzled reads, 2-way = free) ----
    v4f sacc[4] = {(v4f){0,0,0,0},(v4f){0,0,0,0},(v4f){0,0,0,0},(v4f){0,0,0,0}};
    __builtin_amdgcn_s_setprio(1);
#pragma unroll
    for (int ks = 0; ks < 4; ++ks)
#pragma unroll
      for (int tt = 0; tt < 4; ++tt) {
        int krow = tt * 16 + lo;
        v8s kf = *(const v8s*)&Kbuf[krow * 128 + (((ks * 4 + hi) ^ (krow & 7)) * 8)];
        sacc[tt] = __builtin_amdgcn_mfma_f32_16x16x32_bf16(qf[ks], kf, sacc[tt], 0, 0, 0);
      }
    __builtin_amdgcn_s_setprio(0);
    // ---- online softmax ----
    bool masked = (t == qc);
    float al[4], p[4][4];
#pragma unroll
    for (int r = 0; r < 4; ++r) {
      int qg = q0 + 4 * hi + r;
      float s_[4];
#pragma unroll
      for (int tt = 0; tt < 4; ++tt) {
        s_[tt] = sacc[tt][r] * SCALE;
        if (masked && (kv0 + tt * 16 + lo > qg)) s_[tt] = -1e30f;
      }
      float mx = fmaxf(fmaxf(s_[0], s_[1]), fmaxf(s_[2], s_[3]));
      mx = fmaxf(mx, __shfl_xor(mx, 1));
      mx = fmaxf(mx, __shfl_xor(mx, 2));
      mx = fmaxf(mx, __shfl_xor(mx, 4));
      mx = fmaxf(mx, __shfl_xor(mx, 8));
      float mnew = fmaxf(M[r], mx);
      float a = __expf(M[r] - mnew);
      float ps = 0.f;
#pragma unroll
      for (int tt = 0; tt < 4; ++tt) { p[r][tt] = __expf(s_[tt] - mnew); ps += p[r][tt]; }
      ps += __shfl_xor(ps, 1);
      ps += __shfl_xor(ps, 2);
      ps += __shfl_xor(ps, 4);
      ps += __shfl_xor(ps, 8);
      M[r] = mnew; al[r] = a;
      L[r] = L[r] * a + ps;
    }
#pragma unroll
    for (int nt = 0; nt < 8; ++nt)
#pragma unroll
      for (int r = 0; r < 4; ++r) oacc[nt][r] *= al[r];
    // ---- P repack (D-layout -> A-layout) via wave-private LDS ----
#pragma unroll
    for (int r = 0; r < 4; ++r)
#pragma unroll
      for (int tt = 0; tt < 4; ++tt)
        plds[wave][(4 * hi + r) * PST + tt * 16 + lo] = f2b(p[r][tt]);
    v8s pf0 = *(const v8s*)&plds[wave][lo * PST + hi * 8];
    v8s pf1 = *(const v8s*)&plds[wave][lo * PST + 32 + hi * 8];
    // ---- PV from LDS V^T tile ----
    __builtin_amdgcn_s_setprio(1);
#pragma unroll
    for (int nt = 0; nt < 8; ++nt) {
      int vd = nt * 16 + lo;
      v8s vf0 = *(const v8s*)&Vbuf[vd * 64 + ((hi ^ (vd & 7)) * 8)];
      oacc[nt] = __builtin_amdgcn_mfma_f32_16x16x32_bf16(pf0, vf0, oacc[nt], 0, 0, 0);
      v8s vf1 = *(const v8s*)&Vbuf[vd * 64 + (((4 + hi) ^ (vd & 7)) * 8)];
      oacc[nt] = __builtin_amdgcn_mfma_f32_16x16x32_bf16(pf1, vf1, oacc[nt], 0, 0, 0);
    }
    __builtin_amdgcn_s_setprio(0);
    // ---- tile boundary: drain stage(t+1), block-wide barrier ----
    asm volatile("s_waitcnt vmcnt(0)" ::: "memory");
    __builtin_amdgcn_s_barrier();
    __builtin_amdgcn_sched_barrier(0);
    cur ^= 1;
  }
  u16* Op = AO + (size_t)b * SS * DIMM + (size_t)h * HD;
#pragma unroll
  for (int nt = 0; nt < 8; ++nt)
#pragma unroll
    for (int r = 0; r < 4; ++r)
      Op[(size_t)(q0 + 4 * hi + r) * DIMM + nt * 16 + lo] = f2b(oacc[nt][r] / L[r]);
}

extern "C" void kernel_launch(void* const* d_in, const int* in_sizes, int n_in,
                              void* d_out, int out_size, void* d_ws, size_t ws_size,
                              hipStream_t stream) {
  const float* x  = (const float*)d_in[0];
  const float* fc = (const float*)d_in[1];
  const float* fs = (const float*)d_in[2];
  const float* wq = (const float*)d_in[3];
  const float* wk = (const float*)d_in[4];
  const float* wv = (const float*)d_in[5];
  const float* wo = (const float*)d_in[6];
  float* out = (float*)d_out;

  u16* ws  = (u16*)d_ws;
  u16* xb  = ws;               // 16777216
  u16* wqb = xb  + 16777216;   // 4194304
  u16* wkb = wqb + 4194304;    // 1048576
  u16* wvb = wkb + 1048576;    // 1048576
  u16* wob = wvb + 1048576;    // 4194304
  u16* qb  = wob + 4194304;    // 16777216
  u16* kb  = qb  + 16777216;   // 4194304
  u16* vb  = kb  + 4194304;    // 4194304
  u16* ao  = vb  + 4194304;    // 16777216
  u16* vtb = wqb;              // alias: wqb dead after Q GEMM

  convert_all<<<13312, 256, 0, stream>>>(x, wq, wk, wv, wo, xb, wqb, wkb, wvb, wob);
  gemm_bt<0><<<dim3(16, 64), 256, 0, stream>>>(xb, wqb, nullptr, qb, 8192, 2048, 2048);
  gemm_bt<0><<<dim3(4, 64),  256, 0, stream>>>(xb, wkb, nullptr, kb, 8192, 512, 2048);
  gemm_bt<0><<<dim3(4, 64),  256, 0, stream>>>(xb, wvb, nullptr, vb, 8192, 512, 2048);
  rope_all<<<10240, 256, 0, stream>>>(qb, kb, fc, fs);
  transpose_v<<<1024, 256, 0, stream>>>(vb, vtb);
  attn<<<2048, 256, 0, stream>>>(qb, kb, vtb, ao);
  gemm_bt<1><<<dim3(16, 64), 256, 0, stream>>>(ao, wob, out, nullptr, 8192, 2048, 2048);
}

// Round 7
// 578.536 us; speedup vs baseline: 1.6215x; 1.1051x over previous
//
#include <hip/hip_runtime.h>

typedef unsigned short u16;
typedef unsigned int   u32;
typedef short v8s __attribute__((ext_vector_type(8)));
typedef float v4f __attribute__((ext_vector_type(4)));

#define DIMM 2048
#define NH   16
#define NKV  4
#define HD   128
#define BB   8
#define SS   1024
#define KVD  (NKV*HD)   // 512
// SCALE * log2(e) folded into K at RoPE time; attn works in exp2 domain.
#define KSCL 0.12751744f
#define THR  11.5f      // defer-max threshold (log2 domain), p <= 2^11.5
#define EXP2(x) __builtin_amdgcn_exp2f(x)

__device__ __forceinline__ u16 f2b(float f) {
  u32 u = __builtin_bit_cast(u32, f);
  u32 r = (u + 0x7FFFu + ((u >> 16) & 1u)) >> 16;
  return (u16)r;
}
__device__ __forceinline__ float b2f(u16 h) {
  return __builtin_bit_cast(float, (u32)h << 16);
}

typedef const u32 __attribute__((address_space(1)))* gp_t;
typedef u32 __attribute__((address_space(3)))* lp_t;
__device__ __forceinline__ void async16(const u16* g, u16* l) {
  __builtin_amdgcn_global_load_lds((gp_t)g, (lp_t)l, 16, 0, 0);
}

// ---------------- convert f32 -> bf16 (x, wq, wk, wv, wo) ----------------
__global__ __launch_bounds__(256) void convert_all(
    const float* __restrict__ x, const float* __restrict__ wq,
    const float* __restrict__ wk, const float* __restrict__ wv,
    const float* __restrict__ wo,
    u16* __restrict__ xb, u16* __restrict__ wqb, u16* __restrict__ wkb,
    u16* __restrict__ wvb, u16* __restrict__ wob) {
  u32 t = blockIdx.x * 256u + threadIdx.x;
  const float* src; u16* dst; u32 lc;
  if      (t < 2097152u) { src = x;  dst = xb;  lc = t; }
  else if (t < 2621440u) { src = wq; dst = wqb; lc = t - 2097152u; }
  else if (t < 2752512u) { src = wk; dst = wkb; lc = t - 2621440u; }
  else if (t < 2883584u) { src = wv; dst = wvb; lc = t - 2752512u; }
  else                   { src = wo; dst = wob; lc = t - 2883584u; }
  size_t e = (size_t)lc * 8;
  float4 a = *(const float4*)(src + e);
  float4 b = *(const float4*)(src + e + 4);
  uint4 o;
  o.x = (u32)f2b(a.x) | ((u32)f2b(a.y) << 16);
  o.y = (u32)f2b(a.z) | ((u32)f2b(a.w) << 16);
  o.z = (u32)f2b(b.x) | ((u32)f2b(b.y) << 16);
  o.w = (u32)f2b(b.z) | ((u32)f2b(b.w) << 16);
  *(uint4*)(dst + e) = o;
}

// ---------------- GEMM: C(M,N) = A(M,K) @ B(N,K)^T, bf16 in, f32 acc ----------------
template<int OUTF>
__global__ __launch_bounds__(256) void gemm_bt(
    const u16* __restrict__ A, const u16* __restrict__ Bw,
    float* __restrict__ Cf, u16* __restrict__ Cb, int M, int N, int K) {
  __shared__ u16 As[4096];
  __shared__ u16 Bs[4096];
  int wave = threadIdx.x >> 6, lane = threadIdx.x & 63;
  int lo = lane & 15, hi = lane >> 4;
  int wm = wave >> 1, wn = wave & 1;
  int m0 = blockIdx.y * 128, n0 = blockIdx.x * 128;
  v4f acc[4][4] = {};
  for (int k0 = 0; k0 < K; k0 += 32) {
    __syncthreads();
#pragma unroll
    for (int j = 0; j < 2; ++j) {
      int base = (j * 4 + wave) * 512;
      int l = base + lane * 8;
      int row = l >> 5, col = l & 31;
      async16(A  + (size_t)(m0 + row) * K + k0 + col, &As[base]);
      async16(Bw + (size_t)(n0 + row) * K + k0 + col, &Bs[base]);
    }
    __syncthreads();
    v8s af[4], bf[4];
#pragma unroll
    for (int t = 0; t < 4; ++t) {
      af[t] = *(const v8s*)&As[(wm * 64 + t * 16 + lo) * 32 + hi * 8];
      bf[t] = *(const v8s*)&Bs[(wn * 64 + t * 16 + lo) * 32 + hi * 8];
    }
#pragma unroll
    for (int mt = 0; mt < 4; ++mt)
#pragma unroll
      for (int nt = 0; nt < 4; ++nt)
        acc[mt][nt] = __builtin_amdgcn_mfma_f32_16x16x32_bf16(af[mt], bf[nt], acc[mt][nt], 0, 0, 0);
  }
#pragma unroll
  for (int mt = 0; mt < 4; ++mt)
#pragma unroll
    for (int nt = 0; nt < 4; ++nt)
#pragma unroll
      for (int r = 0; r < 4; ++r) {
        int row = m0 + wm * 64 + mt * 16 + 4 * hi + r;
        int col = n0 + wn * 64 + nt * 16 + lo;
        if (OUTF) Cf[(size_t)row * N + col] = acc[mt][nt][r];
        else      Cb[(size_t)row * N + col] = f2b(acc[mt][nt][r]);
      }
}

// ---------------- RoPE on Q and K; K additionally scaled by SCALE*log2e ----------------
__global__ __launch_bounds__(256) void rope_all(
    u16* __restrict__ Qb, u16* __restrict__ Kb,
    const float* __restrict__ fc, const float* __restrict__ fs) {
  u32 t = blockIdx.x * 256u + threadIdx.x;
  u16* buf; u32 row, c8, stride; float sc;
  if (t < 2097152u) { buf = Qb; row = t >> 8; c8 = (t & 255u) * 8u; stride = 2048u; sc = 1.0f; }
  else { u32 lc = t - 2097152u; buf = Kb; row = lc >> 6; c8 = (lc & 63u) * 8u; stride = 512u; sc = KSCL; }
  u32 sp = row & 1023u;
  u32 j0 = (c8 & 127u) >> 1;
  float4 c = *(const float4*)(fc + (size_t)sp * 64 + j0);
  float4 s = *(const float4*)(fs + (size_t)sp * 64 + j0);
  u16* p = buf + (size_t)row * stride + c8;
  uint4 w = *(const uint4*)p;
  u32 wv_[4] = {w.x, w.y, w.z, w.w};
  float cc[4] = {c.x, c.y, c.z, c.w};
  float ss2[4] = {s.x, s.y, s.z, s.w};
#pragma unroll
  for (int i = 0; i < 4; ++i) {
    float tr = b2f((u16)(wv_[i] & 0xFFFFu));
    float ti = b2f((u16)(wv_[i] >> 16));
    float orr = (tr * cc[i] - ti * ss2[i]) * sc;
    float oi  = (tr * ss2[i] + ti * cc[i]) * sc;
    wv_[i] = (u32)f2b(orr) | ((u32)f2b(oi) << 16);
  }
  uint4 o; o.x = wv_[0]; o.y = wv_[1]; o.z = wv_[2]; o.w = wv_[3];
  *(uint4*)p = o;
}

// ---------------- V transpose: vb[b][s][kvh*128+d] -> vt[b][kvh][d][s] ----------------
__global__ __launch_bounds__(256) void transpose_v(
    const u16* __restrict__ vb, u16* __restrict__ vt) {
  __shared__ u32 t32[64][33];
  int blk = blockIdx.x;
  int dt = blk & 1, st = (blk >> 1) & 15, kvh = (blk >> 5) & 3, b = blk >> 7;
  int s0 = st * 64, d0 = dt * 64;
  int tid = threadIdx.x;
  int r = tid >> 3, q = tid & 7;
  const u16* src = vb + (size_t)b * SS * KVD + (size_t)kvh * HD + d0;
#pragma unroll
  for (int p = 0; p < 2; ++p) {
    int row = p * 32 + r;
    uint4 v = *(const uint4*)(src + (size_t)(s0 + row) * KVD + q * 8);
    t32[row][q * 4 + 0] = v.x; t32[row][q * 4 + 1] = v.y;
    t32[row][q * 4 + 2] = v.z; t32[row][q * 4 + 3] = v.w;
  }
  __syncthreads();
  const u16* t16 = (const u16*)t32;
  u16* dst = vt + ((size_t)(b * NKV + kvh) * HD + d0) * SS + s0;
#pragma unroll
  for (int p = 0; p < 2; ++p) {
    int dd = p * 32 + r;
    u16 tmp[8];
#pragma unroll
    for (int j = 0; j < 8; ++j) tmp[j] = t16[(size_t)(q * 8 + j) * 66 + dd];
    *(uint4*)(dst + (size_t)dd * SS + q * 8) = *(uint4*)tmp;
  }
}

// ---------------- Flash attention, causal, GQA ----------------
// grid: B*NH*(S/128) = 1024 blocks; 8 waves/block, wave owns 16 q-rows.
// K/V^T tiles in LDS (dbuf, shared by 8 waves); exp2-domain softmax with
// defer-max + deferred L reduction. LDS = 80KB exactly -> 2 blocks/CU.
__global__ __launch_bounds__(512, 4) void attn(
    const u16* __restrict__ Q, const u16* __restrict__ Kb,
    const u16* __restrict__ Vt, u16* __restrict__ AO) {
  __shared__ u16 Ksh[2][8192];   // [kv][d] 64x128, XOR-swizzled 16B slots
  __shared__ u16 Vsh[2][8192];   // [d][kv] 128x64, XOR-swizzled 16B slots
  __shared__ u16 plds[8][1024];  // per-wave P repack, 16 rows x 64, XOR-swizzled
  int blk = blockIdx.x;
  int qc2 = blk & 7;
  int h   = (blk >> 3) & 15;
  int b   = blk >> 7;
  int wave = threadIdx.x >> 6;
  int lane = threadIdx.x & 63;
  int lo = lane & 15, hi = lane >> 4;
  int q0 = qc2 * 128 + wave * 16;
  int kvh = h >> 2;
  const u16* Qp = Q  + (size_t)b * SS * DIMM + (size_t)h * HD;
  const u16* Kp = Kb + (size_t)b * SS * KVD + (size_t)kvh * HD;
  const u16* Vp = Vt + (size_t)(b * NKV + kvh) * HD * SS;   // [d][s]

  int l4 = lane >> 4, l4s = lane & 15;   // K staging: 4 rows/instr, 16 slots/row
  int l8 = lane >> 3, l8s = lane & 7;    // V staging: 8 rows/instr, 8 slots/row

  v8s qf[4];
#pragma unroll
  for (int ks = 0; ks < 4; ++ks)
    qf[ks] = *(const v8s*)(Qp + (size_t)(q0 + lo) * DIMM + ks * 32 + hi * 8);

  float M[4], Lp[4];
  v4f oacc[8];
#pragma unroll
  for (int r = 0; r < 4; ++r) { M[r] = -1e30f; Lp[r] = 0.f; }
#pragma unroll
  for (int nt = 0; nt < 8; ++nt) oacc[nt] = (v4f){0.f, 0.f, 0.f, 0.f};

  int NT = 2 * qc2 + 2;

  // prologue: stage tile 0 into buf 0 (16 K instrs + 16 V instrs over 8 waves)
#pragma unroll
  for (int i = 0; i < 2; ++i) {
    int instr = wave * 2 + i;
    int row = instr * 4 + l4;
    async16(Kp + (size_t)row * KVD + ((l4s ^ (row & 7)) * 8), &Ksh[0][instr * 512]);
    int d = instr * 8 + l8;
    async16(Vp + (size_t)d * SS + ((l8s ^ (d & 7)) * 8), &Vsh[0][instr * 512]);
  }
  asm volatile("s_waitcnt vmcnt(0)" ::: "memory");
  __builtin_amdgcn_s_barrier();
  __builtin_amdgcn_sched_barrier(0);

  int cur = 0;
  for (int t = 0; t < NT; ++t) {
    int kv0 = t * 64;
    if (t + 1 < NT) {
      int kv1 = kv0 + 64;
#pragma unroll
      for (int i = 0; i < 2; ++i) {
        int instr = wave * 2 + i;
        int row = instr * 4 + l4;
        async16(Kp + (size_t)(kv1 + row) * KVD + ((l4s ^ (row & 7)) * 8),
                &Ksh[cur ^ 1][instr * 512]);
        int d = instr * 8 + l8;
        async16(Vp + (size_t)d * SS + kv1 + ((l8s ^ (d & 7)) * 8),
                &Vsh[cur ^ 1][instr * 512]);
      }
    }
    if (kv0 <= q0 + 15) {   // wave-uniform: tail tiles skip compute
      const u16* Kbuf = Ksh[cur];
      const u16* Vbuf = Vsh[cur];
      // ---- QK^T from LDS ----
      v4f sacc[4] = {(v4f){0,0,0,0},(v4f){0,0,0,0},(v4f){0,0,0,0},(v4f){0,0,0,0}};
      __builtin_amdgcn_s_setprio(1);
#pragma unroll
      for (int ks = 0; ks < 4; ++ks)
#pragma unroll
        for (int tt = 0; tt < 4; ++tt) {
          int krow = tt * 16 + lo;
          v8s kf = *(const v8s*)&Kbuf[krow * 128 + (((ks * 4 + hi) ^ (krow & 7)) * 8)];
          sacc[tt] = __builtin_amdgcn_mfma_f32_16x16x32_bf16(qf[ks], kf, sacc[tt], 0, 0, 0);
        }
      __builtin_amdgcn_s_setprio(0);
      // ---- online softmax (exp2 domain; scale pre-folded into K) ----
      bool masked = (kv0 + 63 > q0);
      float s_[4][4], pmax[4];
#pragma unroll
      for (int r = 0; r < 4; ++r) {
        int qg = q0 + 4 * hi + r;
#pragma unroll
        for (int tt = 0; tt < 4; ++tt) {
          s_[r][tt] = sacc[tt][r];
          if (masked && (kv0 + tt * 16 + lo > qg)) s_[r][tt] = -1e30f;
        }
        pmax[r] = fmaxf(fmaxf(s_[r][0], s_[r][1]), fmaxf(s_[r][2], s_[r][3]));
      }
      bool need = (pmax[0] > M[0] + THR) || (pmax[1] > M[1] + THR) ||
                  (pmax[2] > M[2] + THR) || (pmax[3] > M[3] + THR);
      if (__any(need)) {   // full rescale path (rare after tile 0)
#pragma unroll
        for (int r = 0; r < 4; ++r) {
          float mx = pmax[r];
          mx = fmaxf(mx, __shfl_xor(mx, 1));
          mx = fmaxf(mx, __shfl_xor(mx, 2));
          mx = fmaxf(mx, __shfl_xor(mx, 4));
          mx = fmaxf(mx, __shfl_xor(mx, 8));
          float mnew = fmaxf(M[r], mx);
          float a = EXP2(M[r] - mnew);
          M[r] = mnew; Lp[r] *= a;
#pragma unroll
          for (int nt = 0; nt < 8; ++nt) oacc[nt][r] *= a;
        }
      }
      // p = 2^(s - M), accumulate per-lane L, write swizzled plds
#pragma unroll
      for (int r = 0; r < 4; ++r) {
        int row = 4 * hi + r;
#pragma unroll
        for (int tt = 0; tt < 4; ++tt) {
          float p = EXP2(s_[r][tt] - M[r]);
          Lp[r] += p;
          plds[wave][row * 64 + (((tt * 16) + lo) ^ ((row & 7) << 3))] = f2b(p);
        }
      }
      v8s pf0 = *(const v8s*)&plds[wave][lo * 64 + ((hi ^ (lo & 7)) * 8)];
      v8s pf1 = *(const v8s*)&plds[wave][lo * 64 + (((4 + hi) ^ (lo & 7)) * 8)];
      // ---- PV from LDS V^T tile ----
      __builtin_amdgcn_s_setprio(1);
#pragma unroll
      for (int nt = 0; nt < 8; ++nt) {
        int vd = nt * 16 + lo;
        v8s vf0 = *(const v8s*)&Vbuf[vd * 64 + ((hi ^ (vd & 7)) * 8)];
        oacc[nt] = __builtin_amdgcn_mfma_f32_16x16x32_bf16(pf0, vf0, oacc[nt], 0, 0, 0);
        v8s vf1 = *(const v8s*)&Vbuf[vd * 64 + (((4 + hi) ^ (vd & 7)) * 8)];
        oacc[nt] = __builtin_amdgcn_mfma_f32_16x16x32_bf16(pf1, vf1, oacc[nt], 0, 0, 0);
      }
      __builtin_amdgcn_s_setprio(0);
    }
    // ---- tile boundary: drain stage(t+1), block-wide barrier ----
    asm volatile("s_waitcnt vmcnt(0)" ::: "memory");
    __builtin_amdgcn_s_barrier();
    __builtin_amdgcn_sched_barrier(0);
    cur ^= 1;
  }
  // deferred cross-lane L reduction (kv spans tt in-lane and lo across lanes)
  float L[4];
#pragma unroll
  for (int r = 0; r < 4; ++r) {
    float l = Lp[r];
    l += __shfl_xor(l, 1);
    l += __shfl_xor(l, 2);
    l += __shfl_xor(l, 4);
    l += __shfl_xor(l, 8);
    L[r] = l;
  }
  u16* Op = AO + (size_t)b * SS * DIMM + (size_t)h * HD;
#pragma unroll
  for (int nt = 0; nt < 8; ++nt)
#pragma unroll
    for (int r = 0; r < 4; ++r)
      Op[(size_t)(q0 + 4 * hi + r) * DIMM + nt * 16 + lo] = f2b(oacc[nt][r] / L[r]);
}

extern "C" void kernel_launch(void* const* d_in, const int* in_sizes, int n_in,
                              void* d_out, int out_size, void* d_ws, size_t ws_size,
                              hipStream_t stream) {
  const float* x  = (const float*)d_in[0];
  const float* fc = (const float*)d_in[1];
  const float* fs = (const float*)d_in[2];
  const float* wq = (const float*)d_in[3];
  const float* wk = (const float*)d_in[4];
  const float* wv = (const float*)d_in[5];
  const float* wo = (const float*)d_in[6];
  float* out = (float*)d_out;

  u16* ws  = (u16*)d_ws;
  u16* xb  = ws;               // 16777216
  u16* wqb = xb  + 16777216;   // 4194304
  u16* wkb = wqb + 4194304;    // 1048576
  u16* wvb = wkb + 1048576;    // 1048576
  u16* wob = wvb + 1048576;    // 4194304
  u16* qb  = wob + 4194304;    // 16777216
  u16* kb  = qb  + 16777216;   // 4194304
  u16* vb  = kb  + 4194304;    // 4194304
  u16* ao  = vb  + 4194304;    // 16777216
  u16* vtb = wqb;              // alias: wqb dead after Q GEMM

  convert_all<<<13312, 256, 0, stream>>>(x, wq, wk, wv, wo, xb, wqb, wkb, wvb, wob);
  gemm_bt<0><<<dim3(16, 64), 256, 0, stream>>>(xb, wqb, nullptr, qb, 8192, 2048, 2048);
  gemm_bt<0><<<dim3(4, 64),  256, 0, stream>>>(xb, wkb, nullptr, kb, 8192, 512, 2048);
  gemm_bt<0><<<dim3(4, 64),  256, 0, stream>>>(xb, wvb, nullptr, vb, 8192, 512, 2048);
  rope_all<<<10240, 256, 0, stream>>>(qb, kb, fc, fs);
  transpose_v<<<1024, 256, 0, stream>>>(vb, vtb);
  attn<<<1024, 512, 0, stream>>>(qb, kb, vtb, ao);
  gemm_bt<1><<<dim3(16, 64), 256, 0, stream>>>(ao, wob, out, nullptr, 8192, 2048, 2048);
}

// Round 10
// 481.045 us; speedup vs baseline: 1.9501x; 1.2027x over previous
//
#include <hip/hip_runtime.h>

typedef unsigned short u16;
typedef unsigned int   u32;
typedef short v8s __attribute__((ext_vector_type(8)));
typedef float v4f __attribute__((ext_vector_type(4)));

#define DIMM 2048
#define NH   16
#define NKV  4
#define HD   128
#define BB   8
#define SS   1024
#define QKVD 3072      // fused qkv row stride: [Q 2048 | K 512 | V 512]
// SCALE * log2(e) folded into K at RoPE time; attn works in exp2 domain.
#define KSCL 0.12751744f
#define THR  11.5f
#define EXP2(x) __builtin_amdgcn_exp2f(x)

__device__ __forceinline__ u16 f2b(float f) {
  u32 u = __builtin_bit_cast(u32, f);
  u32 r = (u + 0x7FFFu + ((u >> 16) & 1u)) >> 16;
  return (u16)r;
}
__device__ __forceinline__ float b2f(u16 h) {
  return __builtin_bit_cast(float, (u32)h << 16);
}

typedef const u32 __attribute__((address_space(1)))* gp_t;
typedef u32 __attribute__((address_space(3)))* lp_t;
__device__ __forceinline__ void async16(const u16* g, u16* l) {
  __builtin_amdgcn_global_load_lds((gp_t)g, (lp_t)l, 16, 0, 0);
}

// ---------------- convert f32 -> bf16 (x, wq, wk, wv, wo) ----------------
__global__ __launch_bounds__(256) void convert_all(
    const float* __restrict__ x, const float* __restrict__ wq,
    const float* __restrict__ wk, const float* __restrict__ wv,
    const float* __restrict__ wo,
    u16* __restrict__ xb, u16* __restrict__ wqb, u16* __restrict__ wkb,
    u16* __restrict__ wvb, u16* __restrict__ wob) {
  u32 t = blockIdx.x * 256u + threadIdx.x;
  const float* src; u16* dst; u32 lc;
  if      (t < 2097152u) { src = x;  dst = xb;  lc = t; }
  else if (t < 2621440u) { src = wq; dst = wqb; lc = t - 2097152u; }
  else if (t < 2752512u) { src = wk; dst = wkb; lc = t - 2621440u; }
  else if (t < 2883584u) { src = wv; dst = wvb; lc = t - 2752512u; }
  else                   { src = wo; dst = wob; lc = t - 2883584u; }
  size_t e = (size_t)lc * 8;
  float4 a = *(const float4*)(src + e);
  float4 b = *(const float4*)(src + e + 4);
  uint4 o;
  o.x = (u32)f2b(a.x) | ((u32)f2b(a.y) << 16);
  o.y = (u32)f2b(a.z) | ((u32)f2b(a.w) << 16);
  o.z = (u32)f2b(b.x) | ((u32)f2b(b.y) << 16);
  o.w = (u32)f2b(b.z) | ((u32)f2b(b.w) << 16);
  *(uint4*)(dst + e) = o;
}

// ---------------- GEMM 256x128 tile, BK=64, counted-vmcnt dbuf pipeline ----
// C(M,N) = A(M,K) @ B(N,K)^T. 512 thr = 8 waves (4M x 2N), wave tile 64x64.
// LDS 96KB: A[2][256x64], B[2][128x64], XOR-swizzled (slot^=row&7) via
// pre-swizzled global source. vmcnt(6) steady (next tile's 6 loads in
// flight), vmcnt(0) only on last tile. Stage of kt+2 into buf[cur] only
// after lgkmcnt(0)+barrier proves all waves finished reading buf[cur].
template<int OUTF>
__global__ __launch_bounds__(512, 2) void gemm256(
    const u16* __restrict__ A, const u16* __restrict__ Bw,
    float* __restrict__ Cf, u16* __restrict__ Cb, int M, int N, int K, int NX) {
  __shared__ u16 Ash[2][256 * 64];
  __shared__ u16 Bsh[2][128 * 64];
  int tid = threadIdx.x;
  int wave = tid >> 6, lane = tid & 63;
  int lo = lane & 15, hi = lane >> 4;
  int wr = wave >> 1, wc = wave & 1;
  // bijective XCD swizzle (grid % 8 == 0 guaranteed by caller)
  int nwg = gridDim.x;
  int id = blockIdx.x;
  int swz = (id & 7) * (nwg >> 3) + (id >> 3);
  int bx = swz % NX, by = swz / NX;
  int m0 = by * 256, n0 = bx * 128;
  int NK = K >> 6;

#define STAGE_G(buf, kt)                                                      \
  {                                                                           \
    _Pragma("unroll")                                                         \
    for (int i = 0; i < 4; ++i) {                                             \
      int s = i * 512 + tid;                                                  \
      int row = s >> 3, c = s & 7;                                            \
      async16(A + (size_t)(m0 + row) * K + (kt) * 64 + ((c ^ (row & 7)) * 8), \
              &Ash[buf][s * 8]);                                              \
    }                                                                         \
    _Pragma("unroll")                                                         \
    for (int i = 0; i < 2; ++i) {                                             \
      int s = i * 512 + tid;                                                  \
      int row = s >> 3, c = s & 7;                                            \
      async16(Bw + (size_t)(n0 + row) * K + (kt) * 64 + ((c ^ (row & 7)) * 8),\
              &Bsh[buf][s * 8]);                                              \
    }                                                                         \
  }

  v4f acc[4][4] = {};
  STAGE_G(0, 0);
  STAGE_G(1, 1);
  int cur = 0;
  for (int kt = 0; kt < NK; ++kt) {
    if (kt + 1 < NK) asm volatile("s_waitcnt vmcnt(6)" ::: "memory");
    else             asm volatile("s_waitcnt vmcnt(0)" ::: "memory");
    __builtin_amdgcn_s_barrier();
    const u16* Ab = Ash[cur];
    const u16* Bb = Bsh[cur];
#pragma unroll
    for (int ks2 = 0; ks2 < 2; ++ks2) {
      v8s af[4], bf[4];
#pragma unroll
      for (int mf = 0; mf < 4; ++mf) {
        int row = wr * 64 + mf * 16 + lo;
        af[mf] = *(const v8s*)&Ab[row * 64 + (((ks2 * 4 + hi) ^ (row & 7)) * 8)];
      }
#pragma unroll
      for (int nf = 0; nf < 4; ++nf) {
        int row = wc * 64 + nf * 16 + lo;
        bf[nf] = *(const v8s*)&Bb[row * 64 + (((ks2 * 4 + hi) ^ (row & 7)) * 8)];
      }
      if (ks2 == 1) {
        asm volatile("s_waitcnt lgkmcnt(0)" ::: "memory");
        __builtin_amdgcn_s_barrier();   // all waves done reading buf[cur]
        if (kt + 2 < NK) STAGE_G(cur, kt + 2);
      }
      __builtin_amdgcn_s_setprio(1);
#pragma unroll
      for (int mf = 0; mf < 4; ++mf)
#pragma unroll
        for (int nf = 0; nf < 4; ++nf)
          acc[mf][nf] = __builtin_amdgcn_mfma_f32_16x16x32_bf16(af[mf], bf[nf], acc[mf][nf], 0, 0, 0);
      __builtin_amdgcn_s_setprio(0);
    }
    cur ^= 1;
  }
#pragma unroll
  for (int mf = 0; mf < 4; ++mf)
#pragma unroll
    for (int nf = 0; nf < 4; ++nf)
#pragma unroll
      for (int r = 0; r < 4; ++r) {
        int row = m0 + wr * 64 + mf * 16 + 4 * hi + r;
        int col = n0 + wc * 64 + nf * 16 + lo;
        if (OUTF) Cf[(size_t)row * N + col] = acc[mf][nf][r];
        else      Cb[(size_t)row * N + col] = f2b(acc[mf][nf][r]);
      }
#undef STAGE_G
}

// ---------------- RoPE on fused qkv: Q cols 0..2047, K cols 2048..2559 ----
__global__ __launch_bounds__(256) void rope_all(
    u16* __restrict__ qkv,
    const float* __restrict__ fc, const float* __restrict__ fs) {
  u32 t = blockIdx.x * 256u + threadIdx.x;
  u16* p; u32 row, c8; float sc;
  if (t < 2097152u) { row = t >> 8; c8 = (t & 255u) * 8u;
                      p = qkv + (size_t)row * QKVD + c8; sc = 1.0f; }
  else { u32 lc = t - 2097152u; row = lc >> 6; c8 = (lc & 63u) * 8u;
         p = qkv + (size_t)row * QKVD + 2048 + c8; sc = KSCL; }
  u32 sp = row & 1023u;
  u32 j0 = (c8 & 127u) >> 1;
  float4 c = *(const float4*)(fc + (size_t)sp * 64 + j0);
  float4 s = *(const float4*)(fs + (size_t)sp * 64 + j0);
  uint4 w = *(const uint4*)p;
  u32 wv_[4] = {w.x, w.y, w.z, w.w};
  float cc[4] = {c.x, c.y, c.z, c.w};
  float ss2[4] = {s.x, s.y, s.z, s.w};
#pragma unroll
  for (int i = 0; i < 4; ++i) {
    float tr = b2f((u16)(wv_[i] & 0xFFFFu));
    float ti = b2f((u16)(wv_[i] >> 16));
    float orr = (tr * cc[i] - ti * ss2[i]) * sc;
    float oi  = (tr * ss2[i] + ti * cc[i]) * sc;
    wv_[i] = (u32)f2b(orr) | ((u32)f2b(oi) << 16);
  }
  uint4 o; o.x = wv_[0]; o.y = wv_[1]; o.z = wv_[2]; o.w = wv_[3];
  *(uint4*)p = o;
}

// ---------------- V transpose: qkv[.][2560+kvh*128+d] -> vt[b][kvh][d][s] --
__global__ __launch_bounds__(256) void transpose_v(
    const u16* __restrict__ qkv, u16* __restrict__ vt) {
  __shared__ u32 t32[64][33];
  int blk = blockIdx.x;
  int dt = blk & 1, st = (blk >> 1) & 15, kvh = (blk >> 5) & 3, b = blk >> 7;
  int s0 = st * 64, d0 = dt * 64;
  int tid = threadIdx.x;
  int r = tid >> 3, q = tid & 7;
  const u16* src = qkv + (size_t)b * SS * QKVD + 2560 + kvh * HD + d0;
#pragma unroll
  for (int p = 0; p < 2; ++p) {
    int row = p * 32 + r;
    uint4 v = *(const uint4*)(src + (size_t)(s0 + row) * QKVD + q * 8);
    t32[row][q * 4 + 0] = v.x; t32[row][q * 4 + 1] = v.y;
    t32[row][q * 4 + 2] = v.z; t32[row][q * 4 + 3] = v.w;
  }
  __syncthreads();
  const u16* t16 = (const u16*)t32;
  u16* dst = vt + ((size_t)(b * NKV + kvh) * HD + d0) * SS + s0;
#pragma unroll
  for (int p = 0; p < 2; ++p) {
    int dd = p * 32 + r;
    u16 tmp[8];
#pragma unroll
    for (int j = 0; j < 8; ++j) tmp[j] = t16[(size_t)(q * 8 + j) * 66 + dd];
    *(uint4*)(dst + (size_t)dd * SS + q * 8) = *(uint4*)tmp;
  }
}

// ---------------- Flash attention, causal, GQA (fused qkv input) ----------
__global__ __launch_bounds__(512, 4) void attn(
    const u16* __restrict__ qkv, const u16* __restrict__ Vt,
    u16* __restrict__ AO) {
  __shared__ u16 Ksh[2][8192];
  __shared__ u16 Vsh[2][8192];
  __shared__ u16 plds[8][1024];
  int blk = blockIdx.x;
  int qc2 = blk & 7;
  int h   = (blk >> 3) & 15;
  int b   = blk >> 7;
  int wave = threadIdx.x >> 6;
  int lane = threadIdx.x & 63;
  int lo = lane & 15, hi = lane >> 4;
  int q0 = qc2 * 128 + wave * 16;
  int kvh = h >> 2;
  const u16* Qp = qkv + (size_t)b * SS * QKVD + h * HD;
  const u16* Kp = qkv + (size_t)b * SS * QKVD + 2048 + kvh * HD;
  const u16* Vp = Vt + (size_t)(b * NKV + kvh) * HD * SS;

  int l4 = lane >> 4, l4s = lane & 15;
  int l8 = lane >> 3, l8s = lane & 7;

  v8s qf[4];
#pragma unroll
  for (int ks = 0; ks < 4; ++ks)
    qf[ks] = *(const v8s*)(Qp + (size_t)(q0 + lo) * QKVD + ks * 32 + hi * 8);

  float M[4], Lp[4];
  v4f oacc[8];
#pragma unroll
  for (int r = 0; r < 4; ++r) { M[r] = -1e30f; Lp[r] = 0.f; }
#pragma unroll
  for (int nt = 0; nt < 8; ++nt) oacc[nt] = (v4f){0.f, 0.f, 0.f, 0.f};

  int NT = 2 * qc2 + 2;

#pragma unroll
  for (int i = 0; i < 2; ++i) {
    int instr = wave * 2 + i;
    int row = instr * 4 + l4;
    async16(Kp + (size_t)row * QKVD + ((l4s ^ (row & 7)) * 8), &Ksh[0][instr * 512]);
    int d = instr * 8 + l8;
    async16(Vp + (size_t)d * SS + ((l8s ^ (d & 7)) * 8), &Vsh[0][instr * 512]);
  }
  asm volatile("s_waitcnt vmcnt(0)" ::: "memory");
  __builtin_amdgcn_s_barrier();
  __builtin_amdgcn_sched_barrier(0);

  int cur = 0;
  for (int t = 0; t < NT; ++t) {
    int kv0 = t * 64;
    if (t + 1 < NT) {
      int kv1 = kv0 + 64;
#pragma unroll
      for (int i = 0; i < 2; ++i) {
        int instr = wave * 2 + i;
        int row = instr * 4 + l4;
        async16(Kp + (size_t)(kv1 + row) * QKVD + ((l4s ^ (row & 7)) * 8),
                &Ksh[cur ^ 1][instr * 512]);
        int d = instr * 8 + l8;
        async16(Vp + (size_t)d * SS + kv1 + ((l8s ^ (d & 7)) * 8),
                &Vsh[cur ^ 1][instr * 512]);
      }
    }
    if (kv0 <= q0 + 15) {
      const u16* Kbuf = Ksh[cur];
      const u16* Vbuf = Vsh[cur];
      v4f sacc[4] = {(v4f){0,0,0,0},(v4f){0,0,0,0},(v4f){0,0,0,0},(v4f){0,0,0,0}};
      __builtin_amdgcn_s_setprio(1);
#pragma unroll
      for (int ks = 0; ks < 4; ++ks)
#pragma unroll
        for (int tt = 0; tt < 4; ++tt) {
          int krow = tt * 16 + lo;
          v8s kf = *(const v8s*)&Kbuf[krow * 128 + (((ks * 4 + hi) ^ (krow & 7)) * 8)];
          sacc[tt] = __builtin_amdgcn_mfma_f32_16x16x32_bf16(qf[ks], kf, sacc[tt], 0, 0, 0);
        }
      __builtin_amdgcn_s_setprio(0);
      bool masked = (kv0 + 63 > q0);
      float s_[4][4], pmax[4];
#pragma unroll
      for (int r = 0; r < 4; ++r) {
        int qg = q0 + 4 * hi + r;
#pragma unroll
        for (int tt = 0; tt < 4; ++tt) {
          s_[r][tt] = sacc[tt][r];
          if (masked && (kv0 + tt * 16 + lo > qg)) s_[r][tt] = -1e30f;
        }
        pmax[r] = fmaxf(fmaxf(s_[r][0], s_[r][1]), fmaxf(s_[r][2], s_[r][3]));
      }
      bool need = (pmax[0] > M[0] + THR) || (pmax[1] > M[1] + THR) ||
                  (pmax[2] > M[2] + THR) || (pmax[3] > M[3] + THR);
      if (__any(need)) {
#pragma unroll
        for (int r = 0; r < 4; ++r) {
          float mx = pmax[r];
          mx = fmaxf(mx, __shfl_xor(mx, 1));
          mx = fmaxf(mx, __shfl_xor(mx, 2));
          mx = fmaxf(mx, __shfl_xor(mx, 4));
          mx = fmaxf(mx, __shfl_xor(mx, 8));
          float mnew = fmaxf(M[r], mx);
          float a = EXP2(M[r] - mnew);
          M[r] = mnew; Lp[r] *= a;
#pragma unroll
          for (int nt = 0; nt < 8; ++nt) oacc[nt][r] *= a;
        }
      }
#pragma unroll
      for (int r = 0; r < 4; ++r) {
        int row = 4 * hi + r;
#pragma unroll
        for (int tt = 0; tt < 4; ++tt) {
          float p = EXP2(s_[r][tt] - M[r]);
          Lp[r] += p;
          plds[wave][row * 64 + (((tt * 16) + lo) ^ ((row & 7) << 3))] = f2b(p);
        }
      }
      v8s pf0 = *(const v8s*)&plds[wave][lo * 64 + ((hi ^ (lo & 7)) * 8)];
      v8s pf1 = *(const v8s*)&plds[wave][lo * 64 + (((4 + hi) ^ (lo & 7)) * 8)];
      __builtin_amdgcn_s_setprio(1);
#pragma unroll
      for (int nt = 0; nt < 8; ++nt) {
        int vd = nt * 16 + lo;
        v8s vf0 = *(const v8s*)&Vbuf[vd * 64 + ((hi ^ (vd & 7)) * 8)];
        oacc[nt] = __builtin_amdgcn_mfma_f32_16x16x32_bf16(pf0, vf0, oacc[nt], 0, 0, 0);
        v8s vf1 = *(const v8s*)&Vbuf[vd * 64 + (((4 + hi) ^ (vd & 7)) * 8)];
        oacc[nt] = __builtin_amdgcn_mfma_f32_16x16x32_bf16(pf1, vf1, oacc[nt], 0, 0, 0);
      }
      __builtin_amdgcn_s_setprio(0);
    }
    asm volatile("s_waitcnt vmcnt(0)" ::: "memory");
    __builtin_amdgcn_s_barrier();
    __builtin_amdgcn_sched_barrier(0);
    cur ^= 1;
  }
  float L[4];
#pragma unroll
  for (int r = 0; r < 4; ++r) {
    float l = Lp[r];
    l += __shfl_xor(l, 1);
    l += __shfl_xor(l, 2);
    l += __shfl_xor(l, 4);
    l += __shfl_xor(l, 8);
    L[r] = l;
  }
  u16* Op = AO + (size_t)b * SS * DIMM + h * HD;
#pragma unroll
  for (int nt = 0; nt < 8; ++nt)
#pragma unroll
    for (int r = 0; r < 4; ++r)
      Op[(size_t)(q0 + 4 * hi + r) * DIMM + nt * 16 + lo] = f2b(oacc[nt][r] / L[r]);
}

extern "C" void kernel_launch(void* const* d_in, const int* in_sizes, int n_in,
                              void* d_out, int out_size, void* d_ws, size_t ws_size,
                              hipStream_t stream) {
  const float* x  = (const float*)d_in[0];
  const float* fc = (const float*)d_in[1];
  const float* fs = (const float*)d_in[2];
  const float* wq = (const float*)d_in[3];
  const float* wk = (const float*)d_in[4];
  const float* wv = (const float*)d_in[5];
  const float* wo = (const float*)d_in[6];
  float* out = (float*)d_out;

  u16* ws   = (u16*)d_ws;
  u16* xb   = ws;                   // 16777216
  u16* wqkv = xb + 16777216;        // 6291456 = wq 4194304 | wk 1048576 | wv 1048576
  u16* wob  = wqkv + 6291456;       // 4194304
  u16* qkvb = wob + 4194304;        // 25165824 (8192 x 3072)
  u16* ao   = qkvb + 25165824;      // 16777216
  u16* vtb  = wqkv;                 // alias: wqkv dead after QKV GEMM

  convert_all<<<13312, 256, 0, stream>>>(x, wq, wk, wv, wo, xb,
      wqkv, wqkv + 4194304, wqkv + 5242880, wob);
  gemm256<0><<<768, 512, 0, stream>>>(xb, wqkv, nullptr, qkvb, 8192, 3072, 2048, 24);
  rope_all<<<10240, 256, 0, stream>>>(qkvb, fc, fs);
  transpose_v<<<1024, 256, 0, stream>>>(qkvb, vtb);
  attn<<<1024, 512, 0, stream>>>(qkvb, vtb, ao);
  gemm256<1><<<512, 512, 0, stream>>>(ao, wob, out, nullptr, 8192, 2048, 2048, 16);
}